// Round 13
// baseline (214.328 us; speedup 1.0000x reference)
//
#include <hip/hip_runtime.h>
#include <math.h>

#define NH     12
#define BB     2
#define SEQ    2048
#define DMODEL 768
#define DK     64

typedef __attribute__((ext_vector_type(8))) short short8;   // 8 bf16 = 4 VGPRs
typedef __attribute__((ext_vector_type(4))) short short4v;  // 4 bf16 = 8 B
typedef __attribute__((ext_vector_type(4))) float floatx4;  // MFMA acc

__device__ __forceinline__ unsigned short f2bf(float x) {
    unsigned u = __builtin_bit_cast(unsigned, x);
    u = (u + 0x7fffu + ((u >> 16) & 1u)) >> 16;   // round-to-nearest-even
    return (unsigned short)u;
}
__device__ __forceinline__ unsigned short f2bf_fast(float x) {
    unsigned u = __builtin_bit_cast(unsigned, x);
    return (unsigned short)((u + 0x8000u) >> 16);
}
__device__ __forceinline__ float bf2f(unsigned short h) {
    unsigned u = ((unsigned)h) << 16;
    return __builtin_bit_cast(float, u);
}

// async global -> LDS, 16 B per lane. Dest is wave-uniform base + lane*16.
__device__ __forceinline__ void gld_lds16(const ushort* gptr, ushort* lptr) {
    __builtin_amdgcn_global_load_lds(
        (const __attribute__((address_space(1))) unsigned int*)(const void*)gptr,
        (__attribute__((address_space(3))) unsigned int*)(void*)lptr,
        16, 0, 0);
}

__device__ __forceinline__ short4v shfl8(short4v v, int src) {
    int2 t = __builtin_bit_cast(int2, v);
    t.x = __shfl(t.x, src);
    t.y = __shfl(t.y, src);
    return __builtin_bit_cast(short4v, t);
}

#define SI (BB * SEQ * DMODEL)     // 3,145,728
#define SW (DMODEL * DMODEL)       //   589,824

#define P1_BLOCKS 1024             // flash_p1 grid (4 blocks/CU by LDS; 128
                                   // unified regs/thread caps waves at 4/SIMD
                                   // -- 5 blocks/CU is register-impossible, R10)
#define NPART     8                // steal partitions (~XCDs)
#define ITPP      216              // items per partition (3 bh x 72)
#define SHPP      (P1_BLOCKS / NPART)   // shells per partition = 128

// ---------------------------------------------------------------------------
// cast weights fp32 -> bf16 (9.4 MB). Also initializes the 8 per-partition
// steal counters to SHPP (each shell takes local item (bid>>3) statically).
// ---------------------------------------------------------------------------
__global__ __launch_bounds__(256) void cast_w(
    const float* __restrict__ Wq, const float* __restrict__ Wk,
    const float* __restrict__ Wv, const float* __restrict__ Wo,
    ushort* oWq, ushort* oWk, ushort* oWv, ushort* oWo, int* counter) {
    if (blockIdx.x == 0 && threadIdx.x < NPART) counter[threadIdx.x] = SHPP;
    long i = (long)(blockIdx.x * 256 + threadIdx.x) * 4;
    const float* src; ushort* dst; long off;
    if      (i < 1L * SW) { src = Wq; dst = oWq; off = i; }
    else if (i < 2L * SW) { src = Wk; dst = oWk; off = i - 1L * SW; }
    else if (i < 3L * SW) { src = Wv; dst = oWv; off = i - 2L * SW; }
    else                  { src = Wo; dst = oWo; off = i - 3L * SW; }
    float4 v = *(const float4*)(src + off);
    ushort4 o;
    o.x = f2bf(v.x); o.y = f2bf(v.y); o.z = f2bf(v.z); o.w = f2bf(v.w);
    *(ushort4*)(dst + off) = o;
}

// ---------------------------------------------------------------------------
// bf16 MFMA GEMM: C = A[M,768] @ W[768,768]^T.  TMx128 tile, XOR-swizzled
// LDS, W staged via global_load_lds, AF32 A register-staged fp32->bf16.
//
// R13: TWO K-STEPS PER BARRIER. The compiler emits s_waitcnt vmcnt(0)
// before every s_barrier, so each of the previous 24 barriers paid a
// near-full memory latency against only ~78 cy of MFMA (16 insts) --
// latency-bound at 2.25 grid-limited blocks/CU. Now 4 LDS buffers:
// prefetch steps t+2,t+3 right after the barrier, compute t and t+1
// back-to-back -> 12 barriers, 2x MFMA per drain window. Staging/swizzle/
// fragment code unchanged (R9 lesson: MORE compute per barrier wins; this
// is the inverse of the TM=64 experiment that lost 10%).
// LDS: qkv 64 KB (cap 2 blocks/CU -- makespan-equivalent: 576 blocks
// already ran 3-deep on 64 CUs), gemm_out 48 KB (cap 3, grid 1.5/CU).
// MODE 0: fp32 row-major.  MODE 1: bf16 split-head (b,h,s,dk)*scale.
// MODE 2: bf16 TRANSPOSED split-head (b,h,dk,s) via MFMA operand swap.
// ---------------------------------------------------------------------------
template<bool AF32, int TM>
__device__ __forceinline__ void g_stage_issue(const float* __restrict__ Af,
                                              const ushort* __restrict__ Ab,
                                              const ushort* __restrict__ W,
                                              ushort* __restrict__ Sb,
                                              int m0, int n0, int k0,
                                              int srow, int sch, int schx,
                                              float4* ar0, float4* ar1) {
    constexpr int AIT = TM / 64;
    constexpr int ATS = TM * 32;
    #pragma unroll
    for (int it = 0; it < AIT; ++it) {
        const int r = srow + it * 64;
        if constexpr (AF32) {
            const float* p = Af + (size_t)(m0 + r) * DMODEL + k0 + schx * 8;
            ar0[it] = *(const float4*)p;
            ar1[it] = *(const float4*)(p + 4);
        } else {
            gld_lds16(Ab + (size_t)(m0 + r) * DMODEL + k0 + schx * 8, Sb + r * 32 + sch * 8);
        }
    }
    #pragma unroll
    for (int it = 0; it < 2; ++it) {
        const int r = srow + it * 64;
        gld_lds16(W + (size_t)(n0 + r) * DMODEL + k0 + schx * 8, Sb + ATS + r * 32 + sch * 8);
    }
}

template<int TM>
__device__ __forceinline__ void g_writeA(ushort* __restrict__ Sb, int srow, int sch,
                                         const float4* ar0, const float4* ar1) {
    constexpr int AIT = TM / 64;
    #pragma unroll
    for (int it = 0; it < AIT; ++it) {
        const int r = srow + it * 64;
        short8 s8;
        s8[0] = (short)f2bf_fast(ar0[it].x); s8[1] = (short)f2bf_fast(ar0[it].y);
        s8[2] = (short)f2bf_fast(ar0[it].z); s8[3] = (short)f2bf_fast(ar0[it].w);
        s8[4] = (short)f2bf_fast(ar1[it].x); s8[5] = (short)f2bf_fast(ar1[it].y);
        s8[6] = (short)f2bf_fast(ar1[it].z); s8[7] = (short)f2bf_fast(ar1[it].w);
        *(short8*)(Sb + r * 32 + sch * 8) = s8;
    }
}

template<int MODE, int TM>
__device__ __forceinline__ void g_compute(const ushort* __restrict__ Sb,
                                          floatx4 (&acc)[TM / 32][4],
                                          int wm, int wn, int l15, int quad, int sw2) {
    constexpr int MI  = TM / 32;
    constexpr int ATS = TM * 32;
    const ushort* As  = Sb;
    const ushort* Ws2 = Sb + ATS;
    short8 af[MI], bf[4];
    #pragma unroll
    for (int mi = 0; mi < MI; ++mi)
        af[mi] = *(const short8*)&As[(wm + mi * 16 + l15) * 32 + ((quad ^ sw2) * 8)];
    #pragma unroll
    for (int ni = 0; ni < 4; ++ni)
        bf[ni] = *(const short8*)&Ws2[(wn + ni * 16 + l15) * 32 + ((quad ^ sw2) * 8)];
    #pragma unroll
    for (int mi = 0; mi < MI; ++mi)
        #pragma unroll
        for (int ni = 0; ni < 4; ++ni) {
            if (MODE == 2)
                acc[mi][ni] = __builtin_amdgcn_mfma_f32_16x16x32_bf16(bf[ni], af[mi], acc[mi][ni], 0, 0, 0);
            else
                acc[mi][ni] = __builtin_amdgcn_mfma_f32_16x16x32_bf16(af[mi], bf[ni], acc[mi][ni], 0, 0, 0);
        }
}

template<int MODE, bool AF32, int TM>
__device__ __forceinline__ void gemm_body(ushort* __restrict__ Sbase,
                                          const void* __restrict__ Av,
                                          const ushort* __restrict__ W,
                                          float* __restrict__ outF,
                                          ushort* __restrict__ outH,
                                          float scale) {
    constexpr int ATS = TM * 32;          // A-tile elements per buffer
    constexpr int BST = ATS + 128 * 32;   // LDS buffer stride (A + W tiles)
    constexpr int MI  = TM / 32;          // per-wave 16-row fragments in M
    constexpr int AIT = TM / 64;          // A staging iters (256 thr = 64 rows)
    constexpr int NWG = (TM == 128) ? 192 : 384;   // blocks per GEMM slice

    const int lin = blockIdx.y * 6 + blockIdx.x;
    const int swz = (lin & 7) * (NWG / 8) + (lin >> 3);   // XCD chunking
    const int n0 = (swz % 6) * 128;
    const int m0 = (swz / 6) * TM;

    const int tid  = threadIdx.x;
    const int lane = tid & 63;
    const int wv   = tid >> 6;
    const int l15  = lane & 15;
    const int quad = lane >> 4;
    const int wm = (wv >> 1) * (TM / 2);
    const int wn = (wv & 1) * 64;

    const int srow = tid >> 2;
    const int sch  = tid & 3;
    const int schx = sch ^ ((srow >> 1) & 3);
    const int sw2  = (l15 >> 1) & 3;

    const ushort* Ab = (const ushort*)Av;
    const float*  Af = (const float*)Av;

    floatx4 acc[MI][4];
    #pragma unroll
    for (int i = 0; i < MI; ++i)
        #pragma unroll
        for (int j = 0; j < 4; ++j) acc[i][j] = (floatx4)0.f;

    // A-staging registers: 2 step-slots in flight
    float4 ar0[2][AIT], ar1[2][AIT];

    // prologue: steps 0 -> buf0, 1 -> buf1
    g_stage_issue<AF32, TM>(Af, Ab, W, Sbase,           m0, n0, 0,  srow, sch, schx, ar0[0], ar1[0]);
    g_stage_issue<AF32, TM>(Af, Ab, W, Sbase + BST,     m0, n0, 32, srow, sch, schx, ar0[1], ar1[1]);
    if constexpr (AF32) {
        g_writeA<TM>(Sbase,       srow, sch, ar0[0], ar1[0]);
        g_writeA<TM>(Sbase + BST, srow, sch, ar0[1], ar1[1]);
    }

    const int NS = DMODEL / 32;           // 24 (even; processed 2 per iter)
    for (int t = 0; t < NS; t += 2) {
        __syncthreads();                  // drains steps t,t+1 loads (issued last iter)
        ushort* SbA = Sbase + ((t + 2) & 3) * BST;
        ushort* SbB = Sbase + ((t + 3) & 3) * BST;
        if (t + 2 < NS) {
            g_stage_issue<AF32, TM>(Af, Ab, W, SbA, m0, n0, (t + 2) * 32, srow, sch, schx, ar0[0], ar1[0]);
            g_stage_issue<AF32, TM>(Af, Ab, W, SbB, m0, n0, (t + 3) * 32, srow, sch, schx, ar0[1], ar1[1]);
        }
        g_compute<MODE, TM>(Sbase + (t & 3) * BST,       acc, wm, wn, l15, quad, sw2);
        g_compute<MODE, TM>(Sbase + ((t + 1) & 3) * BST, acc, wm, wn, l15, quad, sw2);
        if constexpr (AF32) {
            if (t + 2 < NS) {
                g_writeA<TM>(SbA, srow, sch, ar0[0], ar1[0]);
                g_writeA<TM>(SbB, srow, sch, ar0[1], ar1[1]);
            }
        }
    }

    #pragma unroll
    for (int mi = 0; mi < MI; ++mi)
        #pragma unroll
        for (int ni = 0; ni < 4; ++ni)
            #pragma unroll
            for (int r = 0; r < 4; ++r) {
                const float v = acc[mi][ni][r] * scale;
                if (MODE == 2) {
                    const int m = m0 + wm + mi * 16 + l15;
                    const int n = n0 + wn + ni * 16 + quad * 4 + r;
                    const int b = m >> 11, s = m & (SEQ - 1);
                    const int h = n >> 6,  dk = n & 63;
                    outH[(((size_t)b * NH + h) * DK + dk) * SEQ + s] = f2bf(v);
                } else {
                    const int m = m0 + wm + mi * 16 + quad * 4 + r;
                    const int n = n0 + wn + ni * 16 + l15;
                    if (MODE == 0) {
                        outF[(size_t)m * DMODEL + n] = v;
                    } else {
                        const int b = m >> 11, s = m & (SEQ - 1);
                        const int h = n >> 6,  dk = n & 63;
                        outH[(((size_t)b * NH + h) * SEQ + s) * DK + dk] = f2bf(v);
                    }
                }
            }
}

#define QSCALE (0.125f * 1.44269504088896f)   // 1/sqrt(dk) * log2(e)

__global__ __launch_bounds__(256) void gemm_qkv(
    const float* Q, const float* K, const float* V,
    const ushort* Wqb, const ushort* Wkb, const ushort* Wvb,
    ushort* qh, ushort* kh, ushort* vhT) {
    __shared__ __align__(16) ushort S[4 * (128 * 32 + 128 * 32)];   // 64 KB
    const int z = blockIdx.z;
    if (z == 0)      gemm_body<1, true, 128>(S, Q, Wqb, nullptr, qh,  QSCALE);
    else if (z == 1) gemm_body<1, true, 128>(S, K, Wkb, nullptr, kh,  1.0f);
    else             gemm_body<2, true, 128>(S, V, Wvb, nullptr, vhT, 1.0f);
}

// 64x128 tile: grid (6,64) = 384 blocks = 1.5 blocks/CU. 48 KB LDS.
__global__ __launch_bounds__(256) void gemm_out(const ushort* A, const ushort* W, float* out) {
    __shared__ __align__(16) ushort S[4 * (64 * 32 + 128 * 32)];    // 48 KB
    gemm_body<0, false, 64>(S, A, W, out, nullptr, 1.0f);
}

// ---------------------------------------------------------------------------
// Flash attention pass 1 (R3-proven, FROZEN): split-K items with FIXED-max
// softmax (partials add). Item = (bh, 128-row q-block Q, slice of up to 4
// k-tiles). Wave owns 32 q-rows.
//
// PER-XCD PARTITIONED WORK-STEALING: 8 counters; shell bid&7 = partition p
// owns bh in {3p..3p+2} (216 items, 128 shells). Each XCD touches 1.6 MB
// K/V + 0.8 MB Q -> L2-resident (measured FETCH 23 MB, WRITE 54 MB).
// Partition cost multisets identical -> balance preserved. Correct under
// ANY bid->XCD mapping. LPT within partition: big-Q slices first.
//
// Session ledger (do not re-try):
//  * Q-block pairing / 864 static items (R4-R8): concurrent-writer L2
//    write-allocate amplification -> WRITE 150-270 MB regardless of
//    per-wave register shape. Steal-serialization keeps in-flight write
//    set small.
//  * 5 blocks/CU (R10): needs <=102 unified regs/thread; this kernel uses
//    ~128 (64 arch + ~64 acc). launch_bounds(256,5) squeeze -> spills ->
//    WRITE 130 MB, 88 us. 4 blocks/CU is the register-occupancy Pareto pt.
//  * gemm_qkv TM=64 (R9): 58.0 vs 52.7 us -- MFMA/barrier halving loses.
// ---------------------------------------------------------------------------
#define NIT   (24 * 72)
#define MBIAS -20.0f
__device__ const int d_offs[17] = {0,1,2,4,6,9,12,16,20,25,30,36,42,49,56,64,72};

__global__ __launch_bounds__(256, 4) void flash_p1(const ushort* __restrict__ qh,
                                                   const ushort* __restrict__ kh,
                                                   const ushort* __restrict__ vhT,
                                                   ushort* __restrict__ ctx,
                                                   ushort* __restrict__ Opart,
                                                   float* __restrict__ lpart,
                                                   int* __restrict__ counter) {
    const int tid  = threadIdx.x;
    const int lane = tid & 63;
    const int wv   = tid >> 6;            // 0..3, owns rows wv*32..wv*32+31
    const int l15  = lane & 15;
    const int quad = lane >> 4;

    __shared__ __align__(16) ushort KV[2][2][64 * 64];   // 32 KB -> 4 blocks/CU
    __shared__ int wshare;

    const int srow = tid >> 3;
    const int sch  = tid & 7;
    const int schx = sch ^ (srow & 7);
    const int swq  = l15 & 7;

    const int srcA = l15 + 32 * (quad & 1);
    const int srcB = srcA + 16;
    const bool hiq = (quad >> 1) != 0;

    // lane-constant LDS fragment columns (bytes are 2*elem; indexing in elems)
    const int colc[2] = { ((quad ^ swq) * 8), (((4 + quad) ^ swq) * 8) };

    const int part   = blockIdx.x & (NPART - 1);
    const int itbase = part * ITPP;
    int lidx = blockIdx.x >> 3;           // static first local item (0..127)
    for (;;) {
        if (lidx >= ITPP) break;
        if (tid == 0) wshare = atomicAdd(counter + part, 1);   // prefetch next
        const int item = itbase + (ITPP - 1 - lidx);           // LPT: big-Q first
        const int bh = item / 72;
        const int r72 = item - bh * 72;
        int Q = 0;
        #pragma unroll
        for (int q = 0; q < 16; ++q) if (r72 >= d_offs[q + 1]) Q = q + 1;
        const int s  = r72 - d_offs[Q];
        const int ns = (Q >> 1) + 1;
        const int b  = bh / NH, h = bh % NH;
        const int qbase = Q * 128;
        const int k_lo = 4 * s;
        const int k_hi = min(4 * s + 3, 2 * Q + 1);

        const ushort* kbase = kh  + (size_t)bh * SEQ * DK;
        const ushort* vbase = vhT + (size_t)bh * DK * SEQ;

        // Q fragments (B-operand): [qs][kc], query = qbase + wv*32 + qs*16 + l15
        short8 qf[2][2];
        #pragma unroll
        for (int qs = 0; qs < 2; ++qs) {
            const ushort* qp = qh + ((size_t)bh * SEQ + qbase + wv * 32 + qs * 16 + l15) * DK;
            qf[qs][0] = *(const short8*)(qp + quad * 8);
            qf[qs][1] = *(const short8*)(qp + 32 + quad * 8);
        }

        // prologue: tile k_lo -> buf 0
        {
            const int k0 = k_lo * 64;
            gld_lds16(kbase + (size_t)(k0 + srow) * DK + schx * 8,        &KV[0][0][srow * 64 + sch * 8]);
            gld_lds16(kbase + (size_t)(k0 + srow + 32) * DK + schx * 8,   &KV[0][0][(srow + 32) * 64 + sch * 8]);
            gld_lds16(vbase + (size_t)srow * SEQ + k0 + schx * 8,         &KV[0][1][srow * 64 + sch * 8]);
            gld_lds16(vbase + (size_t)(srow + 32) * SEQ + k0 + schx * 8,  &KV[0][1][(srow + 32) * 64 + sch * 8]);
        }

        float l_s[2] = {0.f, 0.f};
        floatx4 o_acc[2][4];
        #pragma unroll
        for (int qs = 0; qs < 2; ++qs)
            #pragma unroll
            for (int d = 0; d < 4; ++d) o_acc[qs][d] = (floatx4)0.f;

        for (int kt = k_lo; kt <= k_hi; ++kt) {
            __syncthreads();               // drains own tile-kt loads (issued last iter)
            if (kt < k_hi) {
                const int k0 = (kt + 1) * 64;
                const int bi = (kt + 1 - k_lo) & 1;
                gld_lds16(kbase + (size_t)(k0 + srow) * DK + schx * 8,        &KV[bi][0][srow * 64 + sch * 8]);
                gld_lds16(kbase + (size_t)(k0 + srow + 32) * DK + schx * 8,   &KV[bi][0][(srow + 32) * 64 + sch * 8]);
                gld_lds16(vbase + (size_t)srow * SEQ + k0 + schx * 8,         &KV[bi][1][srow * 64 + sch * 8]);
                gld_lds16(vbase + (size_t)(srow + 32) * SEQ + k0 + schx * 8,  &KV[bi][1][(srow + 32) * 64 + sch * 8]);
            }
            const int cb = (kt - k_lo) & 1;
            const ushort* Ks  = KV[cb][0];
            const ushort* Vts = KV[cb][1];
            const bool diag = (kt >= 2 * Q);

            // QK^T, both qs halves: one K fragment feeds both MFMAs.
            // S^T: C[key = nt*16 + quad*4 + rr][query = l15], init = MBIAS
            floatx4 s_acc[2][4];
            #pragma unroll
            for (int qs = 0; qs < 2; ++qs)
                #pragma unroll
                for (int nt = 0; nt < 4; ++nt) s_acc[qs][nt] = (floatx4)(MBIAS);
            #pragma unroll
            for (int kc = 0; kc < 2; ++kc)
                #pragma unroll
                for (int nt = 0; nt < 4; ++nt) {
                    short8 kf = *(const short8*)&Ks[(nt * 16 + l15) * 64 + colc[kc]];
                    s_acc[0][nt] = __builtin_amdgcn_mfma_f32_16x16x32_bf16(kf, qf[0][kc], s_acc[0][nt], 0, 0, 0);
                    s_acc[1][nt] = __builtin_amdgcn_mfma_f32_16x16x32_bf16(kf, qf[1][kc], s_acc[1][nt], 0, 0, 0);
                }

            if (diag) {
                #pragma unroll
                for (int qs = 0; qs < 2; ++qs) {
                    const int qg = qbase + wv * 32 + qs * 16 + l15;
                    #pragma unroll
                    for (int nt = 0; nt < 4; ++nt)
                        #pragma unroll
                        for (int rr = 0; rr < 4; ++rr)
                            if (kt * 64 + nt * 16 + quad * 4 + rr > qg) s_acc[qs][nt][rr] = -1.0e30f;
                }
            }

            // softmax numerators for both halves (4 independent add chains)
            short4v packed[2][4];
            #pragma unroll
            for (int qs = 0; qs < 2; ++qs) {
                float lp0 = 0.f, lp1 = 0.f, lp2 = 0.f, lp3 = 0.f;
                #pragma unroll
                for (int nt = 0; nt < 4; ++nt)
                    #pragma unroll
                    for (int rr = 0; rr < 4; ++rr) {
                        const float pe = exp2f(s_acc[qs][nt][rr]);
                        if      (rr == 0) lp0 += pe;
                        else if (rr == 1) lp1 += pe;
                        else if (rr == 2) lp2 += pe;
                        else              lp3 += pe;
                        packed[qs][nt][rr] = (short)f2bf_fast(pe);
                    }
                l_s[qs] += (lp0 + lp1) + (lp2 + lp3);
            }

            // P (C-layout) -> A-layout via cross-quad shuffles, then PV.
            // One V fragment feeds both qs MFMAs.
            #pragma unroll
            for (int kc = 0; kc < 2; ++kc) {
                short8 pf[2];
                #pragma unroll
                for (int qs = 0; qs < 2; ++qs) {
                    short4v a0 = shfl8(packed[qs][2 * kc],     srcA);
                    short4v a1 = shfl8(packed[qs][2 * kc + 1], srcA);
                    short4v b0 = shfl8(packed[qs][2 * kc],     srcB);
                    short4v b1 = shfl8(packed[qs][2 * kc + 1], srcB);
                    short4v lo = hiq ? a1 : a0;
                    short4v hi = hiq ? b1 : b0;
                    pf[qs][0] = lo[0]; pf[qs][1] = lo[1]; pf[qs][2] = lo[2]; pf[qs][3] = lo[3];
                    pf[qs][4] = hi[0]; pf[qs][5] = hi[1]; pf[qs][6] = hi[2]; pf[qs][7] = hi[3];
                }
                #pragma unroll
                for (int dkt = 0; dkt < 4; ++dkt) {
                    short8 vf = *(const short8*)&Vts[(dkt * 16 + l15) * 64 + colc[kc]];
                    o_acc[0][dkt] = __builtin_amdgcn_mfma_f32_16x16x32_bf16(pf[0], vf, o_acc[0][dkt], 0, 0, 0);
                    o_acc[1][dkt] = __builtin_amdgcn_mfma_f32_16x16x32_bf16(pf[1], vf, o_acc[1][dkt], 0, 0, 0);
                }
            }
        }

        // l: reduce across quads (same query at l15, +16, +32, +48)
        #pragma unroll
        for (int qs = 0; qs < 2; ++qs) {
            l_s[qs] += __shfl_xor(l_s[qs], 16);
            l_s[qs] += __shfl_xor(l_s[qs], 32);
        }

        if (ns == 1) {
            // full range done: normalize, write ctx (B,S,D)
            #pragma unroll
            for (int qs = 0; qs < 2; ++qs)
                #pragma unroll
                for (int rr = 0; rr < 4; ++rr) {
                    const float lr = __shfl(l_s[qs], quad * 20 + rr);
                    const float inv = 1.f / lr;
                    const int sg = qbase + wv * 32 + qs * 16 + quad * 4 + rr;
                    #pragma unroll
                    for (int dkt = 0; dkt < 4; ++dkt) {
                        const int d = h * DK + dkt * 16 + l15;
                        ctx[((size_t)b * SEQ + sg) * DMODEL + d] = f2bf(o_acc[qs][dkt][rr] * inv);
                    }
                }
        } else {
            const int pid = bh * 70 + (d_offs[Q] - 2) + s;
            ushort* op = Opart + (size_t)pid * (128 * 64);
            #pragma unroll
            for (int qs = 0; qs < 2; ++qs) {
                #pragma unroll
                for (int rr = 0; rr < 4; ++rr) {
                    const int row = wv * 32 + qs * 16 + quad * 4 + rr;
                    #pragma unroll
                    for (int dkt = 0; dkt < 4; ++dkt)
                        op[row * 64 + dkt * 16 + l15] = f2bf(o_acc[qs][dkt][rr]);
                }
                if (quad == 0)
                    lpart[(size_t)pid * 128 + wv * 32 + qs * 16 + l15] = l_s[qs];
            }
        }

        // wshare (written at item start) is visible via the k-loop barriers.
        // readfirstlane -> SGPR so next item's decode is scalar. Barrier AFTER
        // the read: nobody may overwrite wshare or restage KV until all
        // threads have read / finished.
        lidx = __builtin_amdgcn_readfirstlane(wshare);
        __syncthreads();
    }
}

// ---------------------------------------------------------------------------
// Flash pass 2: sum slice partials, normalize, write ctx.
// 4-way row split -- block = (bh, Q>=2, rowgroup rh). Grid 1344 = 5.25
// blocks/CU. Thread handles 8 cols of one row; identical total traffic.
// ---------------------------------------------------------------------------
__global__ __launch_bounds__(256) void flash_combine(const ushort* __restrict__ Opart,
                                                     const float* __restrict__ lpart,
                                                     ushort* __restrict__ ctx) {
    const int blk = blockIdx.x;           // bh*56 + (Q-2)*4 + rh
    const int rh  = blk & 3;
    const int Q   = 2 + ((blk >> 2) % 14);
    const int bh  = blk / 56;
    const int ns = (Q >> 1) + 1;
    const int pbase = bh * 70 + (d_offs[Q] - 2);
    const int b = bh / NH, h = bh % NH;
    const int t = threadIdx.x;
    const int row = rh * 32 + (t >> 3);
    const int c0  = (t & 7) * 8;

    float lt = 0.f;
    for (int s2 = 0; s2 < ns; ++s2) lt += lpart[(size_t)(pbase + s2) * 128 + row];
    const float inv = 1.f / lt;

    float acc[8];
    #pragma unroll
    for (int j = 0; j < 8; ++j) acc[j] = 0.f;
    for (int s2 = 0; s2 < ns; ++s2) {
        const ushort* op = Opart + (size_t)(pbase + s2) * (128 * 64) + row * 64 + c0;
        short8 v = *(const short8*)op;
        #pragma unroll
        for (int e = 0; e < 8; ++e) acc[e] += bf2f((unsigned short)v[e]);
    }
    ushort* dst = ctx + ((size_t)b * SEQ + Q * 128 + row) * DMODEL + h * DK + c0;
    short8 o;
    #pragma unroll
    for (int e = 0; e < 8; ++e) o[e] = (short)f2bf(acc[e] * inv);
    *(short8*)dst = o;
}

// ---------------------------------------------------------------------------
extern "C" void kernel_launch(void* const* d_in, const int* in_sizes, int n_in,
                              void* d_out, int out_size, void* d_ws, size_t ws_size,
                              hipStream_t stream) {
    const float* Q  = (const float*)d_in[0];
    const float* K  = (const float*)d_in[1];
    const float* V  = (const float*)d_in[2];
    const float* Wq = (const float*)d_in[4];
    const float* Wk = (const float*)d_in[5];
    const float* Wv = (const float*)d_in[6];
    const float* Wo = (const float*)d_in[7];

    char* ws = (char*)d_ws;
    const size_t SZ_IN = (size_t)SI * 2;
    const size_t SZ_W  = (size_t)SW * 2;
    ushort* Wqb   = (ushort*)(ws);
    ushort* Wkb   = (ushort*)(ws + SZ_W);
    ushort* Wvb   = (ushort*)(ws + 2 * SZ_W);
    ushort* Wob   = (ushort*)(ws + 3 * SZ_W);
    ushort* qh    = (ushort*)(ws + 4 * SZ_W);
    ushort* kh    = (ushort*)(ws + 4 * SZ_W + SZ_IN);
    ushort* vhT   = (ushort*)(ws + 4 * SZ_W + 2 * SZ_IN);
    ushort* ctx   = (ushort*)(ws + 4 * SZ_W + 3 * SZ_IN);
    ushort* Opart = (ushort*)(ws + 4 * SZ_W + 4 * SZ_IN);                       // 27.5 MB
    float*  lpart = (float*) (ws + 4 * SZ_W + 4 * SZ_IN + (size_t)1680 * 8192 * 2);
    int*    ctr   = (int*)   (ws + 4 * SZ_W + 4 * SZ_IN + (size_t)1680 * 8192 * 2
                                 + (size_t)1680 * 128 * 4);

    dim3 blk(256);
    cast_w<<<dim3(4 * SW / 1024), blk, 0, stream>>>(Wq, Wk, Wv, Wo,
                                                    Wqb, Wkb, Wvb, Wob, ctr);
    gemm_qkv<<<dim3(6, 32, 3), blk, 0, stream>>>(Q, K, V, Wqb, Wkb, Wvb, qh, kh, vhT);
    flash_p1<<<dim3(P1_BLOCKS), blk, 0, stream>>>(qh, kh, vhT, ctx, Opart, lpart, ctr);
    flash_combine<<<dim3(24 * 14 * 4), blk, 0, stream>>>(Opart, lpart, ctx);
    gemm_out<<<dim3(6, 64), blk, 0, stream>>>(ctx, Wob, (float*)d_out);
}

// Round 14
// 204.403 us; speedup vs baseline: 1.0486x; 1.0486x over previous
//
#include <hip/hip_runtime.h>
#include <math.h>

#define NH     12
#define BB     2
#define SEQ    2048
#define DMODEL 768
#define DK     64

typedef __attribute__((ext_vector_type(8))) short short8;   // 8 bf16 = 4 VGPRs
typedef __attribute__((ext_vector_type(4))) short short4v;  // 4 bf16 = 8 B
typedef __attribute__((ext_vector_type(4))) float floatx4;  // MFMA acc

__device__ __forceinline__ unsigned short f2bf(float x) {
    unsigned u = __builtin_bit_cast(unsigned, x);
    u = (u + 0x7fffu + ((u >> 16) & 1u)) >> 16;   // round-to-nearest-even
    return (unsigned short)u;
}
__device__ __forceinline__ unsigned short f2bf_fast(float x) {
    unsigned u = __builtin_bit_cast(unsigned, x);
    return (unsigned short)((u + 0x8000u) >> 16);
}
__device__ __forceinline__ float bf2f(unsigned short h) {
    unsigned u = ((unsigned)h) << 16;
    return __builtin_bit_cast(float, u);
}

// async global -> LDS, 16 B per lane. Dest is wave-uniform base + lane*16.
__device__ __forceinline__ void gld_lds16(const ushort* gptr, ushort* lptr) {
    __builtin_amdgcn_global_load_lds(
        (const __attribute__((address_space(1))) unsigned int*)(const void*)gptr,
        (__attribute__((address_space(3))) unsigned int*)(void*)lptr,
        16, 0, 0);
}

__device__ __forceinline__ short4v shfl8(short4v v, int src) {
    int2 t = __builtin_bit_cast(int2, v);
    t.x = __shfl(t.x, src);
    t.y = __shfl(t.y, src);
    return __builtin_bit_cast(short4v, t);
}

#define SI (BB * SEQ * DMODEL)     // 3,145,728
#define SW (DMODEL * DMODEL)       //   589,824

#define P1_BLOCKS 1024             // flash_p1 grid (4 blocks/CU by LDS; 128
                                   // unified regs/thread caps waves at 4/SIMD
                                   // -- 5 blocks/CU is register-impossible, R10)
#define NPART     8                // steal partitions (~XCDs)
#define ITPP      216              // items per partition (3 bh x 72)
#define SHPP      (P1_BLOCKS / NPART)   // shells per partition = 128

// ---------------------------------------------------------------------------
// cast weights fp32 -> bf16 (9.4 MB). Also initializes the 8 per-partition
// steal counters to SHPP (each shell takes local item (bid>>3) statically).
// ---------------------------------------------------------------------------
__global__ __launch_bounds__(256) void cast_w(
    const float* __restrict__ Wq, const float* __restrict__ Wk,
    const float* __restrict__ Wv, const float* __restrict__ Wo,
    ushort* oWq, ushort* oWk, ushort* oWv, ushort* oWo, int* counter) {
    if (blockIdx.x == 0 && threadIdx.x < NPART) counter[threadIdx.x] = SHPP;
    long i = (long)(blockIdx.x * 256 + threadIdx.x) * 4;
    const float* src; ushort* dst; long off;
    if      (i < 1L * SW) { src = Wq; dst = oWq; off = i; }
    else if (i < 2L * SW) { src = Wk; dst = oWk; off = i - 1L * SW; }
    else if (i < 3L * SW) { src = Wv; dst = oWv; off = i - 2L * SW; }
    else                  { src = Wo; dst = oWo; off = i - 3L * SW; }
    float4 v = *(const float4*)(src + off);
    ushort4 o;
    o.x = f2bf(v.x); o.y = f2bf(v.y); o.z = f2bf(v.z); o.w = f2bf(v.w);
    *(ushort4*)(dst + off) = o;
}

// ---------------------------------------------------------------------------
// bf16 MFMA GEMM: C = A[M,768] @ W[768,768]^T.  TMx128 tile, BK=32 double-
// buffered, XOR-swizzled LDS, 1 barrier/step. W staged via global_load_lds.
// XCD-chunk block swizzle (T1): each XCD owns a contiguous m-chunk x all 6 n.
// AF32: A fp32 in global, converted during register-staged LDS write.
// MODE 0: fp32 row-major.  MODE 1: bf16 split-head (b,h,s,dk)*scale.
// MODE 2: bf16 TRANSPOSED split-head (b,h,dk,s) via MFMA operand swap.
// TM: 128 (grid y=32) or 64 (grid y=64).
// Ledger (GEMM axis is CLOSED -- both directions measured worse):
//  * TM=64 for qkv (R9): 58.0 vs 52.7 us -- MFMA/barrier halving loses.
//  * 2 K-steps/barrier, 64 KB LDS (R13): 56.2 us -- occupancy 2.25->2
//    blocks/CU + VGPR 84->116 outweighed halved barrier count.
// ---------------------------------------------------------------------------
template<int MODE, bool AF32, int TM>
__device__ __forceinline__ void gemm_body(ushort* __restrict__ Sbase,
                                          const void* __restrict__ Av,
                                          const ushort* __restrict__ W,
                                          float* __restrict__ outF,
                                          ushort* __restrict__ outH,
                                          float scale) {
    constexpr int ATS = TM * 32;          // A-tile elements per buffer
    constexpr int BST = ATS + 128 * 32;   // LDS buffer stride (A + W tiles)
    constexpr int MI  = TM / 32;          // per-wave 16-row fragments in M
    constexpr int AIT = TM / 64;          // A staging iters (256 thr = 64 rows)
    constexpr int NWG = (TM == 128) ? 192 : 384;   // blocks per GEMM slice

    const int lin = blockIdx.y * 6 + blockIdx.x;
    const int swz = (lin & 7) * (NWG / 8) + (lin >> 3);   // XCD chunking
    const int n0 = (swz % 6) * 128;
    const int m0 = (swz / 6) * TM;

    const int tid  = threadIdx.x;
    const int lane = tid & 63;
    const int wv   = tid >> 6;
    const int l15  = lane & 15;
    const int quad = lane >> 4;
    const int wm = (wv >> 1) * (TM / 2);
    const int wn = (wv & 1) * 64;

    const int srow = tid >> 2;
    const int sch  = tid & 3;
    const int schx = sch ^ ((srow >> 1) & 3);
    const int sw2  = (l15 >> 1) & 3;

    const ushort* Ab = (const ushort*)Av;
    const float*  Af = (const float*)Av;

    floatx4 acc[MI][4];
    #pragma unroll
    for (int i = 0; i < MI; ++i)
        #pragma unroll
        for (int j = 0; j < 4; ++j) acc[i][j] = (floatx4)0.f;

    float4 ar0[2], ar1[2];
    #pragma unroll
    for (int it = 0; it < AIT; ++it) {
        const int r = srow + it * 64;
        if (AF32) {
            const float* p = Af + (size_t)(m0 + r) * DMODEL + schx * 8;
            ar0[it] = *(const float4*)p;
            ar1[it] = *(const float4*)(p + 4);
        } else {
            gld_lds16(Ab + (size_t)(m0 + r) * DMODEL + schx * 8, Sbase + r * 32 + sch * 8);
        }
    }
    #pragma unroll
    for (int it = 0; it < 2; ++it) {
        const int r = srow + it * 64;
        gld_lds16(W + (size_t)(n0 + r) * DMODEL + schx * 8, Sbase + ATS + r * 32 + sch * 8);
    }
    if (AF32) {
        #pragma unroll
        for (int it = 0; it < AIT; ++it) {
            const int r = srow + it * 64;
            short8 s8;
            s8[0] = (short)f2bf_fast(ar0[it].x); s8[1] = (short)f2bf_fast(ar0[it].y);
            s8[2] = (short)f2bf_fast(ar0[it].z); s8[3] = (short)f2bf_fast(ar0[it].w);
            s8[4] = (short)f2bf_fast(ar1[it].x); s8[5] = (short)f2bf_fast(ar1[it].y);
            s8[6] = (short)f2bf_fast(ar1[it].z); s8[7] = (short)f2bf_fast(ar1[it].w);
            *(short8*)(Sbase + r * 32 + sch * 8) = s8;
        }
    }

    const int NS = DMODEL / 32;
    for (int t = 0; t < NS; ++t) {
        __syncthreads();
        const int bi = (t + 1) & 1;
        ushort* SbufN = Sbase + bi * BST;
        if (t + 1 < NS) {
            const int k0 = (t + 1) * 32;
            #pragma unroll
            for (int it = 0; it < AIT; ++it) {
                const int r = srow + it * 64;
                if (AF32) {
                    const float* p = Af + (size_t)(m0 + r) * DMODEL + k0 + schx * 8;
                    ar0[it] = *(const float4*)p;
                    ar1[it] = *(const float4*)(p + 4);
                } else {
                    gld_lds16(Ab + (size_t)(m0 + r) * DMODEL + k0 + schx * 8, SbufN + r * 32 + sch * 8);
                }
            }
            #pragma unroll
            for (int it = 0; it < 2; ++it) {
                const int r = srow + it * 64;
                gld_lds16(W + (size_t)(n0 + r) * DMODEL + k0 + schx * 8, SbufN + ATS + r * 32 + sch * 8);
            }
        }
        const ushort* As  = Sbase + (t & 1) * BST;
        const ushort* Ws2 = As + ATS;
        short8 af[MI], bf[4];
        #pragma unroll
        for (int mi = 0; mi < MI; ++mi)
            af[mi] = *(const short8*)&As[(wm + mi * 16 + l15) * 32 + ((quad ^ sw2) * 8)];
        #pragma unroll
        for (int ni = 0; ni < 4; ++ni)
            bf[ni] = *(const short8*)&Ws2[(wn + ni * 16 + l15) * 32 + ((quad ^ sw2) * 8)];
        #pragma unroll
        for (int mi = 0; mi < MI; ++mi)
            #pragma unroll
            for (int ni = 0; ni < 4; ++ni) {
                if (MODE == 2)
                    acc[mi][ni] = __builtin_amdgcn_mfma_f32_16x16x32_bf16(bf[ni], af[mi], acc[mi][ni], 0, 0, 0);
                else
                    acc[mi][ni] = __builtin_amdgcn_mfma_f32_16x16x32_bf16(af[mi], bf[ni], acc[mi][ni], 0, 0, 0);
            }
        if (AF32 && t + 1 < NS) {
            #pragma unroll
            for (int it = 0; it < AIT; ++it) {
                const int r = srow + it * 64;
                short8 s8;
                s8[0] = (short)f2bf_fast(ar0[it].x); s8[1] = (short)f2bf_fast(ar0[it].y);
                s8[2] = (short)f2bf_fast(ar0[it].z); s8[3] = (short)f2bf_fast(ar0[it].w);
                s8[4] = (short)f2bf_fast(ar1[it].x); s8[5] = (short)f2bf_fast(ar1[it].y);
                s8[6] = (short)f2bf_fast(ar1[it].z); s8[7] = (short)f2bf_fast(ar1[it].w);
                *(short8*)(SbufN + r * 32 + sch * 8) = s8;
            }
        }
    }

    #pragma unroll
    for (int mi = 0; mi < MI; ++mi)
        #pragma unroll
        for (int ni = 0; ni < 4; ++ni)
            #pragma unroll
            for (int r = 0; r < 4; ++r) {
                const float v = acc[mi][ni][r] * scale;
                if (MODE == 2) {
                    const int m = m0 + wm + mi * 16 + l15;
                    const int n = n0 + wn + ni * 16 + quad * 4 + r;
                    const int b = m >> 11, s = m & (SEQ - 1);
                    const int h = n >> 6,  dk = n & 63;
                    outH[(((size_t)b * NH + h) * DK + dk) * SEQ + s] = f2bf(v);
                } else {
                    const int m = m0 + wm + mi * 16 + quad * 4 + r;
                    const int n = n0 + wn + ni * 16 + l15;
                    if (MODE == 0) {
                        outF[(size_t)m * DMODEL + n] = v;
                    } else {
                        const int b = m >> 11, s = m & (SEQ - 1);
                        const int h = n >> 6,  dk = n & 63;
                        outH[(((size_t)b * NH + h) * SEQ + s) * DK + dk] = f2bf(v);
                    }
                }
            }
}

#define QSCALE (0.125f * 1.44269504088896f)   // 1/sqrt(dk) * log2(e)

__global__ __launch_bounds__(256) void gemm_qkv(
    const float* Q, const float* K, const float* V,
    const ushort* Wqb, const ushort* Wkb, const ushort* Wvb,
    ushort* qh, ushort* kh, ushort* vhT) {
    __shared__ __align__(16) ushort S[2 * (128 * 32 + 128 * 32)];   // 32 KB
    const int z = blockIdx.z;
    if (z == 0)      gemm_body<1, true, 128>(S, Q, Wqb, nullptr, qh,  QSCALE);
    else if (z == 1) gemm_body<1, true, 128>(S, K, Wkb, nullptr, kh,  1.0f);
    else             gemm_body<2, true, 128>(S, V, Wvb, nullptr, vhT, 1.0f);
}

// 64x128 tile: grid (6,64) = 384 blocks = 1.5 blocks/CU. 24 KB LDS.
__global__ __launch_bounds__(256) void gemm_out(const ushort* A, const ushort* W, float* out) {
    __shared__ __align__(16) ushort S[2 * (64 * 32 + 128 * 32)];    // 24 KB
    gemm_body<0, false, 64>(S, A, W, out, nullptr, 1.0f);
}

// ---------------------------------------------------------------------------
// Flash attention pass 1 (R3-proven, FROZEN): split-K items with FIXED-max
// softmax (partials add). Item = (bh, 128-row q-block Q, slice of up to 4
// k-tiles). Wave owns 32 q-rows.
//
// PER-XCD PARTITIONED WORK-STEALING: 8 counters; shell bid&7 = partition p
// owns bh in {3p..3p+2} (216 items, 128 shells). Each XCD touches 1.6 MB
// K/V + 0.8 MB Q -> L2-resident (measured FETCH 23 MB, WRITE 54 MB).
// Partition cost multisets identical -> balance preserved. Correct under
// ANY bid->XCD mapping. LPT within partition: big-Q slices first.
//
// Session ledger (do not re-try):
//  * Q-block pairing / 864 static items (R4-R8): concurrent-writer L2
//    write-allocate amplification -> WRITE 150-270 MB regardless of
//    per-wave register shape. Steal-serialization keeps in-flight write
//    set small.
//  * 5 blocks/CU (R10): needs <=102 unified regs/thread; this kernel uses
//    ~128 (64 arch + ~64 acc). launch_bounds(256,5) squeeze -> spills ->
//    WRITE 130 MB, 88 us. 4 blocks/CU is the register-occupancy Pareto pt.
//  * gemm_qkv TM=64 (R9) and 2-step/barrier (R13): both regress.
// ---------------------------------------------------------------------------
#define NIT   (24 * 72)
#define MBIAS -20.0f
__device__ const int d_offs[17] = {0,1,2,4,6,9,12,16,20,25,30,36,42,49,56,64,72};

__global__ __launch_bounds__(256, 4) void flash_p1(const ushort* __restrict__ qh,
                                                   const ushort* __restrict__ kh,
                                                   const ushort* __restrict__ vhT,
                                                   ushort* __restrict__ ctx,
                                                   ushort* __restrict__ Opart,
                                                   float* __restrict__ lpart,
                                                   int* __restrict__ counter) {
    const int tid  = threadIdx.x;
    const int lane = tid & 63;
    const int wv   = tid >> 6;            // 0..3, owns rows wv*32..wv*32+31
    const int l15  = lane & 15;
    const int quad = lane >> 4;

    __shared__ __align__(16) ushort KV[2][2][64 * 64];   // 32 KB -> 4 blocks/CU
    __shared__ int wshare;

    const int srow = tid >> 3;
    const int sch  = tid & 7;
    const int schx = sch ^ (srow & 7);
    const int swq  = l15 & 7;

    const int srcA = l15 + 32 * (quad & 1);
    const int srcB = srcA + 16;
    const bool hiq = (quad >> 1) != 0;

    // lane-constant LDS fragment columns (bytes are 2*elem; indexing in elems)
    const int colc[2] = { ((quad ^ swq) * 8), (((4 + quad) ^ swq) * 8) };

    const int part   = blockIdx.x & (NPART - 1);
    const int itbase = part * ITPP;
    int lidx = blockIdx.x >> 3;           // static first local item (0..127)
    for (;;) {
        if (lidx >= ITPP) break;
        if (tid == 0) wshare = atomicAdd(counter + part, 1);   // prefetch next
        const int item = itbase + (ITPP - 1 - lidx);           // LPT: big-Q first
        const int bh = item / 72;
        const int r72 = item - bh * 72;
        int Q = 0;
        #pragma unroll
        for (int q = 0; q < 16; ++q) if (r72 >= d_offs[q + 1]) Q = q + 1;
        const int s  = r72 - d_offs[Q];
        const int ns = (Q >> 1) + 1;
        const int b  = bh / NH, h = bh % NH;
        const int qbase = Q * 128;
        const int k_lo = 4 * s;
        const int k_hi = min(4 * s + 3, 2 * Q + 1);

        const ushort* kbase = kh  + (size_t)bh * SEQ * DK;
        const ushort* vbase = vhT + (size_t)bh * DK * SEQ;

        // Q fragments (B-operand): [qs][kc], query = qbase + wv*32 + qs*16 + l15
        short8 qf[2][2];
        #pragma unroll
        for (int qs = 0; qs < 2; ++qs) {
            const ushort* qp = qh + ((size_t)bh * SEQ + qbase + wv * 32 + qs * 16 + l15) * DK;
            qf[qs][0] = *(const short8*)(qp + quad * 8);
            qf[qs][1] = *(const short8*)(qp + 32 + quad * 8);
        }

        // prologue: tile k_lo -> buf 0
        {
            const int k0 = k_lo * 64;
            gld_lds16(kbase + (size_t)(k0 + srow) * DK + schx * 8,        &KV[0][0][srow * 64 + sch * 8]);
            gld_lds16(kbase + (size_t)(k0 + srow + 32) * DK + schx * 8,   &KV[0][0][(srow + 32) * 64 + sch * 8]);
            gld_lds16(vbase + (size_t)srow * SEQ + k0 + schx * 8,         &KV[0][1][srow * 64 + sch * 8]);
            gld_lds16(vbase + (size_t)(srow + 32) * SEQ + k0 + schx * 8,  &KV[0][1][(srow + 32) * 64 + sch * 8]);
        }

        float l_s[2] = {0.f, 0.f};
        floatx4 o_acc[2][4];
        #pragma unroll
        for (int qs = 0; qs < 2; ++qs)
            #pragma unroll
            for (int d = 0; d < 4; ++d) o_acc[qs][d] = (floatx4)0.f;

        for (int kt = k_lo; kt <= k_hi; ++kt) {
            __syncthreads();               // drains own tile-kt loads (issued last iter)
            if (kt < k_hi) {
                const int k0 = (kt + 1) * 64;
                const int bi = (kt + 1 - k_lo) & 1;
                gld_lds16(kbase + (size_t)(k0 + srow) * DK + schx * 8,        &KV[bi][0][srow * 64 + sch * 8]);
                gld_lds16(kbase + (size_t)(k0 + srow + 32) * DK + schx * 8,   &KV[bi][0][(srow + 32) * 64 + sch * 8]);
                gld_lds16(vbase + (size_t)srow * SEQ + k0 + schx * 8,         &KV[bi][1][srow * 64 + sch * 8]);
                gld_lds16(vbase + (size_t)(srow + 32) * SEQ + k0 + schx * 8,  &KV[bi][1][(srow + 32) * 64 + sch * 8]);
            }
            const int cb = (kt - k_lo) & 1;
            const ushort* Ks  = KV[cb][0];
            const ushort* Vts = KV[cb][1];
            const bool diag = (kt >= 2 * Q);

            // QK^T, both qs halves: one K fragment feeds both MFMAs.
            // S^T: C[key = nt*16 + quad*4 + rr][query = l15], init = MBIAS
            floatx4 s_acc[2][4];
            #pragma unroll
            for (int qs = 0; qs < 2; ++qs)
                #pragma unroll
                for (int nt = 0; nt < 4; ++nt) s_acc[qs][nt] = (floatx4)(MBIAS);
            #pragma unroll
            for (int kc = 0; kc < 2; ++kc)
                #pragma unroll
                for (int nt = 0; nt < 4; ++nt) {
                    short8 kf = *(const short8*)&Ks[(nt * 16 + l15) * 64 + colc[kc]];
                    s_acc[0][nt] = __builtin_amdgcn_mfma_f32_16x16x32_bf16(kf, qf[0][kc], s_acc[0][nt], 0, 0, 0);
                    s_acc[1][nt] = __builtin_amdgcn_mfma_f32_16x16x32_bf16(kf, qf[1][kc], s_acc[1][nt], 0, 0, 0);
                }

            if (diag) {
                #pragma unroll
                for (int qs = 0; qs < 2; ++qs) {
                    const int qg = qbase + wv * 32 + qs * 16 + l15;
                    #pragma unroll
                    for (int nt = 0; nt < 4; ++nt)
                        #pragma unroll
                        for (int rr = 0; rr < 4; ++rr)
                            if (kt * 64 + nt * 16 + quad * 4 + rr > qg) s_acc[qs][nt][rr] = -1.0e30f;
                }
            }

            // softmax numerators for both halves (4 independent add chains)
            short4v packed[2][4];
            #pragma unroll
            for (int qs = 0; qs < 2; ++qs) {
                float lp0 = 0.f, lp1 = 0.f, lp2 = 0.f, lp3 = 0.f;
                #pragma unroll
                for (int nt = 0; nt < 4; ++nt)
                    #pragma unroll
                    for (int rr = 0; rr < 4; ++rr) {
                        const float pe = exp2f(s_acc[qs][nt][rr]);
                        if      (rr == 0) lp0 += pe;
                        else if (rr == 1) lp1 += pe;
                        else if (rr == 2) lp2 += pe;
                        else              lp3 += pe;
                        packed[qs][nt][rr] = (short)f2bf_fast(pe);
                    }
                l_s[qs] += (lp0 + lp1) + (lp2 + lp3);
            }

            // P (C-layout) -> A-layout via cross-quad shuffles, then PV.
            // One V fragment feeds both qs MFMAs.
            #pragma unroll
            for (int kc = 0; kc < 2; ++kc) {
                short8 pf[2];
                #pragma unroll
                for (int qs = 0; qs < 2; ++qs) {
                    short4v a0 = shfl8(packed[qs][2 * kc],     srcA);
                    short4v a1 = shfl8(packed[qs][2 * kc + 1], srcA);
                    short4v b0 = shfl8(packed[qs][2 * kc],     srcB);
                    short4v b1 = shfl8(packed[qs][2 * kc + 1], srcB);
                    short4v lo = hiq ? a1 : a0;
                    short4v hi = hiq ? b1 : b0;
                    pf[qs][0] = lo[0]; pf[qs][1] = lo[1]; pf[qs][2] = lo[2]; pf[qs][3] = lo[3];
                    pf[qs][4] = hi[0]; pf[qs][5] = hi[1]; pf[qs][6] = hi[2]; pf[qs][7] = hi[3];
                }
                #pragma unroll
                for (int dkt = 0; dkt < 4; ++dkt) {
                    short8 vf = *(const short8*)&Vts[(dkt * 16 + l15) * 64 + colc[kc]];
                    o_acc[0][dkt] = __builtin_amdgcn_mfma_f32_16x16x32_bf16(pf[0], vf, o_acc[0][dkt], 0, 0, 0);
                    o_acc[1][dkt] = __builtin_amdgcn_mfma_f32_16x16x32_bf16(pf[1], vf, o_acc[1][dkt], 0, 0, 0);
                }
            }
        }

        // l: reduce across quads (same query at l15, +16, +32, +48)
        #pragma unroll
        for (int qs = 0; qs < 2; ++qs) {
            l_s[qs] += __shfl_xor(l_s[qs], 16);
            l_s[qs] += __shfl_xor(l_s[qs], 32);
        }

        if (ns == 1) {
            // full range done: normalize, write ctx (B,S,D)
            #pragma unroll
            for (int qs = 0; qs < 2; ++qs)
                #pragma unroll
                for (int rr = 0; rr < 4; ++rr) {
                    const float lr = __shfl(l_s[qs], quad * 20 + rr);
                    const float inv = 1.f / lr;
                    const int sg = qbase + wv * 32 + qs * 16 + quad * 4 + rr;
                    #pragma unroll
                    for (int dkt = 0; dkt < 4; ++dkt) {
                        const int d = h * DK + dkt * 16 + l15;
                        ctx[((size_t)b * SEQ + sg) * DMODEL + d] = f2bf(o_acc[qs][dkt][rr] * inv);
                    }
                }
        } else {
            const int pid = bh * 70 + (d_offs[Q] - 2) + s;
            ushort* op = Opart + (size_t)pid * (128 * 64);
            #pragma unroll
            for (int qs = 0; qs < 2; ++qs) {
                #pragma unroll
                for (int rr = 0; rr < 4; ++rr) {
                    const int row = wv * 32 + qs * 16 + quad * 4 + rr;
                    #pragma unroll
                    for (int dkt = 0; dkt < 4; ++dkt)
                        op[row * 64 + dkt * 16 + l15] = f2bf(o_acc[qs][dkt][rr]);
                }
                if (quad == 0)
                    lpart[(size_t)pid * 128 + wv * 32 + qs * 16 + l15] = l_s[qs];
            }
        }

        // wshare (written at item start) is visible via the k-loop barriers.
        // readfirstlane -> SGPR so next item's decode is scalar. Barrier AFTER
        // the read: nobody may overwrite wshare or restage KV until all
        // threads have read / finished.
        lidx = __builtin_amdgcn_readfirstlane(wshare);
        __syncthreads();
    }
}

// ---------------------------------------------------------------------------
// Flash pass 2: sum slice partials, normalize, write ctx.
// 4-way row split -- block = (bh, Q>=2, rowgroup rh). Grid 1344 = 5.25
// blocks/CU. Thread handles 8 cols of one row; identical total traffic.
// ---------------------------------------------------------------------------
__global__ __launch_bounds__(256) void flash_combine(const ushort* __restrict__ Opart,
                                                     const float* __restrict__ lpart,
                                                     ushort* __restrict__ ctx) {
    const int blk = blockIdx.x;           // bh*56 + (Q-2)*4 + rh
    const int rh  = blk & 3;
    const int Q   = 2 + ((blk >> 2) % 14);
    const int bh  = blk / 56;
    const int ns = (Q >> 1) + 1;
    const int pbase = bh * 70 + (d_offs[Q] - 2);
    const int b = bh / NH, h = bh % NH;
    const int t = threadIdx.x;
    const int row = rh * 32 + (t >> 3);
    const int c0  = (t & 7) * 8;

    float lt = 0.f;
    for (int s2 = 0; s2 < ns; ++s2) lt += lpart[(size_t)(pbase + s2) * 128 + row];
    const float inv = 1.f / lt;

    float acc[8];
    #pragma unroll
    for (int j = 0; j < 8; ++j) acc[j] = 0.f;
    for (int s2 = 0; s2 < ns; ++s2) {
        const ushort* op = Opart + (size_t)(pbase + s2) * (128 * 64) + row * 64 + c0;
        short8 v = *(const short8*)op;
        #pragma unroll
        for (int e = 0; e < 8; ++e) acc[e] += bf2f((unsigned short)v[e]);
    }
    ushort* dst = ctx + ((size_t)b * SEQ + Q * 128 + row) * DMODEL + h * DK + c0;
    short8 o;
    #pragma unroll
    for (int e = 0; e < 8; ++e) o[e] = (short)f2bf(acc[e] * inv);
    *(short8*)dst = o;
}

// ---------------------------------------------------------------------------
extern "C" void kernel_launch(void* const* d_in, const int* in_sizes, int n_in,
                              void* d_out, int out_size, void* d_ws, size_t ws_size,
                              hipStream_t stream) {
    const float* Q  = (const float*)d_in[0];
    const float* K  = (const float*)d_in[1];
    const float* V  = (const float*)d_in[2];
    const float* Wq = (const float*)d_in[4];
    const float* Wk = (const float*)d_in[5];
    const float* Wv = (const float*)d_in[6];
    const float* Wo = (const float*)d_in[7];

    char* ws = (char*)d_ws;
    const size_t SZ_IN = (size_t)SI * 2;
    const size_t SZ_W  = (size_t)SW * 2;
    ushort* Wqb   = (ushort*)(ws);
    ushort* Wkb   = (ushort*)(ws + SZ_W);
    ushort* Wvb   = (ushort*)(ws + 2 * SZ_W);
    ushort* Wob   = (ushort*)(ws + 3 * SZ_W);
    ushort* qh    = (ushort*)(ws + 4 * SZ_W);
    ushort* kh    = (ushort*)(ws + 4 * SZ_W + SZ_IN);
    ushort* vhT   = (ushort*)(ws + 4 * SZ_W + 2 * SZ_IN);
    ushort* ctx   = (ushort*)(ws + 4 * SZ_W + 3 * SZ_IN);
    ushort* Opart = (ushort*)(ws + 4 * SZ_W + 4 * SZ_IN);                       // 27.5 MB
    float*  lpart = (float*) (ws + 4 * SZ_W + 4 * SZ_IN + (size_t)1680 * 8192 * 2);
    int*    ctr   = (int*)   (ws + 4 * SZ_W + 4 * SZ_IN + (size_t)1680 * 8192 * 2
                                 + (size_t)1680 * 128 * 4);

    dim3 blk(256);
    cast_w<<<dim3(4 * SW / 1024), blk, 0, stream>>>(Wq, Wk, Wv, Wo,
                                                    Wqb, Wkb, Wvb, Wob, ctr);
    gemm_qkv<<<dim3(6, 32, 3), blk, 0, stream>>>(Q, K, V, Wqb, Wkb, Wvb, qh, kh, vhT);
    flash_p1<<<dim3(P1_BLOCKS), blk, 0, stream>>>(qh, kh, vhT, ctx, Opart, lpart, ctr);
    flash_combine<<<dim3(24 * 14 * 4), blk, 0, stream>>>(Opart, lpart, ctx);
    gemm_out<<<dim3(6, 64), blk, 0, stream>>>(ctx, Wob, (float*)d_out);
}